// Round 1
// baseline (2635.090 us; speedup 1.0000x reference)
//
#include <hip/hip_runtime.h>
#include <math.h>

// LGMLoss pipeline, fp32 correctness-first version.
// dist[b,c] = sum_d ff*inv + f*(-2*mu*inv) + sum_d mu^2*inv
// logits = x - lse(x), x = -0.5*(slog[c] + dist)
// margin: dist scaled by 1.1 at c==label[b] before the same transform.
// Outputs: [logits BxC][margin BxC][likelihood][cdist][reg]

#define ALPHA_F 0.1f

// ---------------- K1: per-class stats + transposed weights ----------------
__global__ __launch_bounds__(256) void k1_classstats(
    const float* __restrict__ centers, const float* __restrict__ log_covs,
    float* __restrict__ winv_t, float* __restrict__ wcen_t,
    float* __restrict__ sumc, float* __restrict__ slog, int C, int D)
{
    __shared__ float Wi[32][132];
    __shared__ float Wc[32][132];
    int tid = threadIdx.x;
    int c0 = blockIdx.x * 32;
    int tc = tid >> 3;   // 0..31 class within tile
    int tl = tid & 7;    // 0..7 lane within class
    int c = c0 + tc;
    const float4* cen4 = (const float4*)(centers + (size_t)c * D);
    const float4* lc4  = (const float4*)(log_covs + (size_t)c * D);
    float psum = 0.f, plog = 0.f;
    #pragma unroll
    for (int q = 0; q < 4; ++q) {
        int d4 = tl + q * 8;            // float4 index 0..31 (D=128)
        float4 cv = cen4[d4];
        float4 lv = lc4[d4];
        float cs[4] = {cv.x, cv.y, cv.z, cv.w};
        float ls[4] = {lv.x, lv.y, lv.z, lv.w};
        #pragma unroll
        for (int j = 0; j < 4; ++j) {
            float inv = __expf(-ls[j]);
            int d = d4 * 4 + j;
            Wi[tc][d] = inv;
            Wc[tc][d] = -2.f * cs[j] * inv;
            psum = fmaf(cs[j] * cs[j], inv, psum);
            plog += ls[j];
        }
    }
    psum += __shfl_down(psum, 4, 8);
    psum += __shfl_down(psum, 2, 8);
    psum += __shfl_down(psum, 1, 8);
    plog += __shfl_down(plog, 4, 8);
    plog += __shfl_down(plog, 2, 8);
    plog += __shfl_down(plog, 1, 8);
    if (tl == 0) { sumc[c] = psum; slog[c] = plog; }
    __syncthreads();
    int cc = tid & 31, dr = tid >> 5;
    for (int d = dr; d < D; d += 8) {
        winv_t[(size_t)d * C + c0 + cc] = Wi[cc][d];
        wcen_t[(size_t)d * C + c0 + cc] = Wc[cc][d];
    }
}

// ---------------- K2: dist GEMM + partial logsumexp ----------------
// block: 256 threads; tile 32 rows x 256 cols; thread: 8 rows x 4 cols.
__global__ __launch_bounds__(256) void k2_gemm(
    const float* __restrict__ feat, const int* __restrict__ label,
    const float* __restrict__ winv_t, const float* __restrict__ wcen_t,
    const float* __restrict__ sumc, const float* __restrict__ slog,
    float* __restrict__ dist_out, float* __restrict__ partials,
    int B, int C, int D, int NCB)
{
    __shared__ float ffP[32 * 128];
    __shared__ float fP[32 * 128];
    __shared__ int lab_s[32];
    int tid = threadIdx.x;
    int cb = blockIdx.x, rb = blockIdx.y;
    int row0 = rb * 32, c0 = cb * 256;

    // stage feat rows: ff and f planes, natural [r][d] layout (conflict-free)
    for (int i = tid; i < 32 * 32; i += 256) {   // 32 rows x 32 float4
        int r = i >> 5, dq = i & 31;
        float4 f4 = *(const float4*)(feat + (size_t)(row0 + r) * D + dq * 4);
        float4 s4;
        s4.x = f4.x * f4.x; s4.y = f4.y * f4.y; s4.z = f4.z * f4.z; s4.w = f4.w * f4.w;
        *(float4*)&ffP[r * 128 + dq * 4] = s4;
        *(float4*)&fP[r * 128 + dq * 4] = f4;
    }
    if (tid < 32) lab_s[tid] = label[row0 + tid];
    __syncthreads();

    int tc = tid & 63;   // col group within wave
    int tr = tid >> 6;   // wave id -> row group
    const float* wiP = winv_t + (size_t)c0 + tc * 4;
    const float* wcP = wcen_t + (size_t)c0 + tc * 4;

    float acc[8][4];
    #pragma unroll
    for (int r = 0; r < 8; ++r)
        #pragma unroll
        for (int j = 0; j < 4; ++j) acc[r][j] = 0.f;

    for (int d = 0; d < 128; d += 4) {
        float4 wi[4], wc[4];
        #pragma unroll
        for (int k = 0; k < 4; ++k) {
            wi[k] = *(const float4*)(wiP + (size_t)(d + k) * C);
            wc[k] = *(const float4*)(wcP + (size_t)(d + k) * C);
        }
        #pragma unroll
        for (int rr = 0; rr < 8; ++rr) {
            int r = tr * 8 + rr;
            float4 aff = *(const float4*)&ffP[r * 128 + d];   // broadcast reads
            float4 af  = *(const float4*)&fP[r * 128 + d];
            #pragma unroll
            for (int j = 0; j < 4; ++j) {
                float w0 = (&wi[0].x)[j], c0v = (&wc[0].x)[j];
                float w1 = (&wi[1].x)[j], c1v = (&wc[1].x)[j];
                float w2 = (&wi[2].x)[j], c2v = (&wc[2].x)[j];
                float w3 = (&wi[3].x)[j], c3v = (&wc[3].x)[j];
                float a = acc[rr][j];
                a = fmaf(aff.x, w0, a); a = fmaf(af.x, c0v, a);
                a = fmaf(aff.y, w1, a); a = fmaf(af.y, c1v, a);
                a = fmaf(aff.z, w2, a); a = fmaf(af.z, c2v, a);
                a = fmaf(aff.w, w3, a); a = fmaf(af.w, c3v, a);
                acc[rr][j] = a;
            }
        }
    }

    // epilogue: add sumc, store dist, per-row online lse partials (2 variants)
    int cbase = c0 + tc * 4;
    float4 sc = *(const float4*)(sumc + cbase);
    float4 sl = *(const float4*)(slog + cbase);
    #pragma unroll
    for (int rr = 0; rr < 8; ++rr) {
        int row = row0 + tr * 8 + rr;
        int lab = lab_s[tr * 8 + rr];
        float d0 = acc[rr][0] + sc.x;
        float d1 = acc[rr][1] + sc.y;
        float d2 = acc[rr][2] + sc.z;
        float d3 = acc[rr][3] + sc.w;
        float4 dv = {d0, d1, d2, d3};
        *(float4*)(dist_out + (size_t)row * C + cbase) = dv;
        float x0 = -0.5f * (sl.x + d0);
        float x1 = -0.5f * (sl.y + d1);
        float x2 = -0.5f * (sl.z + d2);
        float x3 = -0.5f * (sl.w + d3);
        float m0 = (cbase + 0 == lab) ? (1.f + ALPHA_F) : 1.f;
        float m1_ = (cbase + 1 == lab) ? (1.f + ALPHA_F) : 1.f;
        float m2_ = (cbase + 2 == lab) ? (1.f + ALPHA_F) : 1.f;
        float m3_ = (cbase + 3 == lab) ? (1.f + ALPHA_F) : 1.f;
        float y0 = -0.5f * (sl.x + d0 * m0);
        float y1 = -0.5f * (sl.y + d1 * m1_);
        float y2 = -0.5f * (sl.z + d2 * m2_);
        float y3 = -0.5f * (sl.w + d3 * m3_);
        float mA = fmaxf(fmaxf(x0, x1), fmaxf(x2, x3));
        float sA = expf(x0 - mA) + expf(x1 - mA) + expf(x2 - mA) + expf(x3 - mA);
        float mB = fmaxf(fmaxf(y0, y1), fmaxf(y2, y3));
        float sB = expf(y0 - mB) + expf(y1 - mB) + expf(y2 - mB) + expf(y3 - mB);
        #pragma unroll
        for (int off = 32; off > 0; off >>= 1) {
            float om = __shfl_xor(mA, off), os = __shfl_xor(sA, off);
            float M = fmaxf(mA, om);
            sA = sA * expf(mA - M) + os * expf(om - M); mA = M;
            om = __shfl_xor(mB, off); os = __shfl_xor(sB, off);
            M = fmaxf(mB, om);
            sB = sB * expf(mB - M) + os * expf(om - M); mB = M;
        }
        if (tc == 0) {
            float4 p = {mA, sA, mB, sB};
            *(float4*)(partials + ((size_t)row * NCB + cb) * 4) = p;
        }
    }
}

// ---------------- K3: per-row combine + row scalars ----------------
__global__ __launch_bounds__(64) void k3_rows(
    const float* __restrict__ partials, const float* __restrict__ feat,
    const float* __restrict__ centers, const int* __restrict__ label,
    const float* __restrict__ slog,
    float* __restrict__ lse, float* __restrict__ lse_m,
    float* __restrict__ rowcd, float* __restrict__ rowdet,
    int B, int C, int D, int NCB)
{
    int b = blockIdx.x;
    int lane = threadIdx.x;
    float mA = -INFINITY, sA = 0.f, mB = -INFINITY, sB = 0.f;
    for (int j = lane; j < NCB; j += 64) {
        float4 p = *(const float4*)(partials + ((size_t)b * NCB + j) * 4);
        float M = fmaxf(mA, p.x);
        sA = sA * expf(mA - M) + p.y * expf(p.x - M); mA = M;
        M = fmaxf(mB, p.z);
        sB = sB * expf(mB - M) + p.w * expf(p.z - M); mB = M;
    }
    #pragma unroll
    for (int off = 32; off > 0; off >>= 1) {
        float om = __shfl_xor(mA, off), os = __shfl_xor(sA, off);
        float M = fmaxf(mA, om);
        if (M > -INFINITY) { sA = sA * expf(mA - M) + os * expf(om - M); mA = M; }
        om = __shfl_xor(mB, off); os = __shfl_xor(sB, off);
        M = fmaxf(mB, om);
        if (M > -INFINITY) { sB = sB * expf(mB - M) + os * expf(om - M); mB = M; }
    }
    int lab = label[b];
    float cd = 0.f;
    for (int d = lane; d < D; d += 64) {
        float df = feat[(size_t)b * D + d] - centers[(size_t)lab * D + d];
        cd = fmaf(df, df, cd);
    }
    #pragma unroll
    for (int off = 32; off > 0; off >>= 1) cd += __shfl_xor(cd, off);
    if (lane == 0) {
        lse[b] = mA + logf(sA);
        lse_m[b] = mB + logf(sB);
        rowcd[b] = cd;
        rowdet[b] = slog[lab];
    }
}

// ---------------- K4: final elementwise logits/margin ----------------
__global__ __launch_bounds__(256) void k4_final(
    float* __restrict__ out_logits, float* __restrict__ out_margin,
    const float* __restrict__ slog, const int* __restrict__ label,
    const float* __restrict__ lse, const float* __restrict__ lse_m, int C)
{
    int b = blockIdx.y;
    int c = (blockIdx.x * 256 + threadIdx.x) * 4;
    if (c >= C) return;
    size_t idx = (size_t)b * C + c;
    float4 dv = *(const float4*)(out_logits + idx);
    float4 sl = *(const float4*)(slog + c);
    float L = lse[b], Lm = lse_m[b];
    int lab = label[b];
    float4 lg, mg;
    float m0 = (c + 0 == lab) ? (1.f + ALPHA_F) : 1.f;
    float m1 = (c + 1 == lab) ? (1.f + ALPHA_F) : 1.f;
    float m2 = (c + 2 == lab) ? (1.f + ALPHA_F) : 1.f;
    float m3 = (c + 3 == lab) ? (1.f + ALPHA_F) : 1.f;
    lg.x = -0.5f * (sl.x + dv.x) - L;
    lg.y = -0.5f * (sl.y + dv.y) - L;
    lg.z = -0.5f * (sl.z + dv.z) - L;
    lg.w = -0.5f * (sl.w + dv.w) - L;
    mg.x = -0.5f * (sl.x + dv.x * m0) - Lm;
    mg.y = -0.5f * (sl.y + dv.y * m1) - Lm;
    mg.z = -0.5f * (sl.z + dv.z * m2) - Lm;
    mg.w = -0.5f * (sl.w + dv.w * m3) - Lm;
    *(float4*)(out_logits + idx) = lg;
    *(float4*)(out_margin + idx) = mg;
}

// ---------------- K5: scalar outputs ----------------
__global__ __launch_bounds__(256) void k5_scalars(
    const float* __restrict__ rowcd, const float* __restrict__ rowdet,
    float* __restrict__ out3, int B)
{
    __shared__ float redc[4], redd[4];
    int tid = threadIdx.x;
    float cd = 0.f, dt = 0.f;
    for (int b = tid; b < B; b += 256) { cd += rowcd[b]; dt += rowdet[b]; }
    #pragma unroll
    for (int off = 32; off > 0; off >>= 1) {
        cd += __shfl_xor(cd, off);
        dt += __shfl_xor(dt, off);
    }
    if ((tid & 63) == 0) { redc[tid >> 6] = cd; redd[tid >> 6] = dt; }
    __syncthreads();
    if (tid == 0) {
        cd = redc[0] + redc[1] + redc[2] + redc[3];
        dt = redd[0] + redd[1] + redd[2] + redd[3];
        float cdist = 0.5f * cd;
        float reg = 0.5f * (dt + 1e-8f);
        float likelihood = (cdist - reg) / (float)B;
        out3[0] = likelihood;
        out3[1] = cdist;
        out3[2] = reg;
    }
}

extern "C" void kernel_launch(void* const* d_in, const int* in_sizes, int n_in,
                              void* d_out, int out_size, void* d_ws, size_t ws_size,
                              hipStream_t stream) {
    const float* feat     = (const float*)d_in[0];
    const int*   label    = (const int*)d_in[1];
    const float* centers  = (const float*)d_in[2];
    const float* log_covs = (const float*)d_in[3];

    int B = in_sizes[1];
    int D = in_sizes[0] / B;          // 128
    int C = in_sizes[2] / D;          // 32000
    int NCB = (C + 255) / 256;        // 125

    float* ws = (float*)d_ws;
    size_t DC = (size_t)D * C;
    float* winv_t   = ws;
    float* wcen_t   = winv_t + DC;
    float* sumc     = wcen_t + DC;
    float* slog     = sumc + C;
    float* partials = slog + C;
    float* lse      = partials + (size_t)B * NCB * 4;
    float* lse_m    = lse + B;
    float* rowcd    = lse_m + B;
    float* rowdet   = rowcd + B;

    float* out        = (float*)d_out;
    float* out_margin = out + (size_t)B * C;
    float* out3       = out + 2 * (size_t)B * C;

    k1_classstats<<<C / 32, 256, 0, stream>>>(centers, log_covs, winv_t, wcen_t,
                                              sumc, slog, C, D);
    k2_gemm<<<dim3(NCB, B / 32), 256, 0, stream>>>(feat, label, winv_t, wcen_t,
                                                   sumc, slog, out, partials,
                                                   B, C, D, NCB);
    k3_rows<<<B, 64, 0, stream>>>(partials, feat, centers, label, slog,
                                  lse, lse_m, rowcd, rowdet, B, C, D, NCB);
    k4_final<<<dim3((C / 4 + 255) / 256, B), 256, 0, stream>>>(out, out_margin,
                                                               slog, label, lse,
                                                               lse_m, C);
    k5_scalars<<<1, 256, 0, stream>>>(rowcd, rowdet, out3, B);
}